// Round 1
// baseline (1101.391 us; speedup 1.0000x reference)
//
#include <hip/hip_runtime.h>
#include <cstdint>
#include <cstddef>

// Problem constants
#define RN 12800   // routes
#define CN 25      // caps
#define ON 64      // out channels
#define IN_ 8      // in channels
#define BN 8       // batch
#define SOUT (BN*CN*ON)   // 12800 output elems

// Per-wave c assignment: wave w in [0,8) owns c = {w, w+8, w+16}; wave 0 also owns c=24.
// lane = o (64 lanes = 64 output channels).
//
// MODE 0: iteration 0 (c uniform = 1/R): accumulate S[b,c,o] = sum_r u_hat.
// MODE 1: fused agreement(v0) + softmax-numerator pass: per route compute
//         b1[r,c] = mean_b sum_o u_hat*v0 (store), e=exp(b1),
//         accumulate S += e*u_hat and Z[c] += e.
// MODE 2: same but b2 = b1(loaded) + mean_b sum_o u_hat*v1 (no store needed).
template<int MODE>
__global__ void __launch_bounds__(512, 4)
caps_pass(const float* __restrict__ x, const float* __restrict__ W,
          const float* __restrict__ vin, const float* __restrict__ bin,
          float* __restrict__ bout, float* __restrict__ Sp, float* __restrict__ Zp,
          int rpw)
{
    const int wg   = blockIdx.x;
    const int wave = threadIdx.x >> 6;
    const int lane = threadIdx.x & 63;
    const int NC   = (wave == 0) ? 4 : 3;
    int cs[4];
    cs[0] = wave; cs[1] = wave + 8; cs[2] = wave + 16; cs[3] = 24;

    float acc[4][BN];
    #pragma unroll
    for (int k = 0; k < 4; ++k)
        #pragma unroll
        for (int b = 0; b < BN; ++b) acc[k][b] = 0.f;

    // v fragment for my (c, o=lane): [k][b]
    float vreg[4][BN];
    if (MODE >= 1) {
        #pragma unroll
        for (int k = 0; k < 4; ++k) {
            if (k < NC) {
                const int c = cs[k];
                #pragma unroll
                for (int b = 0; b < BN; ++b)
                    vreg[k][b] = vin[(b * CN + c) * ON + lane];
            }
        }
    }
    float zacc[4] = {0.f, 0.f, 0.f, 0.f};

    const int r0 = wg * rpw;
    for (int ri = 0; ri < rpw; ++ri) {
        const int r = r0 + ri;
        if (r >= RN) break;

        // Load W fragments for my c's: W[r][c][o=lane][0:8] -> 2x float4 each.
        float4 w0[4], w1[4];
        #pragma unroll
        for (int k = 0; k < 4; ++k) {
            if (k < NC) {
                const float4* wp = reinterpret_cast<const float4*>(
                    W + ((((size_t)r * CN + cs[k]) * ON + lane) * IN_));
                w0[k] = wp[0];
                w1[k] = wp[1];
            }
        }

        if (MODE == 0) {
            #pragma unroll
            for (int b = 0; b < BN; ++b) {
                const float4* xp = reinterpret_cast<const float4*>(
                    x + (((size_t)b * RN + r) * IN_));
                const float4 xa = xp[0], xb = xp[1];
                #pragma unroll
                for (int k = 0; k < 4; ++k) {
                    if (k < NC) {
                        float u = w0[k].x*xa.x + w0[k].y*xa.y + w0[k].z*xa.z + w0[k].w*xa.w
                                + w1[k].x*xb.x + w1[k].y*xb.y + w1[k].z*xb.z + w1[k].w*xb.w;
                        acc[k][b] += u;
                    }
                }
            }
        } else {
            // Phase A: per-lane agreement partials p[k] = sum_b u*v (o=lane slice)
            float p[4] = {0.f, 0.f, 0.f, 0.f};
            #pragma unroll
            for (int b = 0; b < BN; ++b) {
                const float4* xp = reinterpret_cast<const float4*>(
                    x + (((size_t)b * RN + r) * IN_));
                const float4 xa = xp[0], xb = xp[1];
                #pragma unroll
                for (int k = 0; k < 4; ++k) {
                    if (k < NC) {
                        float u = w0[k].x*xa.x + w0[k].y*xa.y + w0[k].z*xa.z + w0[k].w*xa.w
                                + w1[k].x*xb.x + w1[k].y*xb.y + w1[k].z*xb.z + w1[k].w*xb.w;
                        p[k] += u * vreg[k][b];
                    }
                }
            }
            // Reduce p over 64 lanes (sum over o); butterfly leaves result in all lanes.
            #pragma unroll
            for (int k = 0; k < 4; ++k) {
                float t = p[k];
                #pragma unroll
                for (int off = 32; off > 0; off >>= 1) t += __shfl_xor(t, off, 64);
                p[k] = t;
            }
            float e[4] = {0.f, 0.f, 0.f, 0.f};
            #pragma unroll
            for (int k = 0; k < 4; ++k) {
                if (k < NC) {
                    float bn = p[k] * (1.0f / BN);
                    if (MODE == 2) bn += bin[(size_t)r * CN + cs[k]];
                    if (MODE == 1 && lane == 0) bout[(size_t)r * CN + cs[k]] = bn;
                    e[k] = expf(bn);
                    zacc[k] += e[k];
                }
            }
            // Phase B: recompute u (x reloads hit cache), accumulate e*u.
            #pragma unroll
            for (int b = 0; b < BN; ++b) {
                const float4* xp = reinterpret_cast<const float4*>(
                    x + (((size_t)b * RN + r) * IN_));
                const float4 xa = xp[0], xb = xp[1];
                #pragma unroll
                for (int k = 0; k < 4; ++k) {
                    if (k < NC) {
                        float u = w0[k].x*xa.x + w0[k].y*xa.y + w0[k].z*xa.z + w0[k].w*xa.w
                                + w1[k].x*xb.x + w1[k].y*xb.y + w1[k].z*xb.z + w1[k].w*xb.w;
                        acc[k][b] += e[k] * u;
                    }
                }
            }
        }
    }

    // Write per-WG partials (every WG writes all its owned slots; no init needed).
    float* sp = Sp + (size_t)wg * SOUT;
    #pragma unroll
    for (int k = 0; k < 4; ++k) {
        if (k < NC) {
            #pragma unroll
            for (int b = 0; b < BN; ++b)
                sp[(b * CN + cs[k]) * ON + lane] = acc[k][b];
        }
    }
    if (MODE >= 1 && lane == 0) {
        #pragma unroll
        for (int k = 0; k < 4; ++k)
            if (k < NC) Zp[wg * 32 + cs[k]] = zacc[k];
    }
}

// PASS 0: z = R (uniform softmax of zeros); PASS 1: z from Zp; PASS 2: same + final output.
template<int PASS>
__global__ void caps_finalize(const float* __restrict__ Sp, const float* __restrict__ Zp,
                              float* __restrict__ vout, int nwg)
{
    const int idx = blockIdx.x * blockDim.x + threadIdx.x;
    if (idx >= SOUT) return;
    const int c = (idx >> 6) % CN;
    float s = 0.f;
    for (int w = 0; w < nwg; ++w) s += Sp[(size_t)w * SOUT + idx];
    float z;
    if (PASS == 0) {
        z = (float)RN;
    } else {
        z = 0.f;
        for (int w = 0; w < nwg; ++w) z += Zp[w * 32 + c];
    }
    s /= z;
    // squash: s*|s|/(1+s^2)
    vout[idx] = s * fabsf(s) / (1.f + s * s);
}

extern "C" void kernel_launch(void* const* d_in, const int* in_sizes, int n_in,
                              void* d_out, int out_size, void* d_ws, size_t ws_size,
                              hipStream_t stream)
{
    const float* x = (const float*)d_in[0];   // [B, R, I]
    const float* W = (const float*)d_in[1];   // [R, C, O, I]
    float* out = (float*)d_out;               // [B, C, O, 1] flat = 12800
    float* ws = (float*)d_ws;

    // Workspace layout (floats): v[12800] | b1[R*C=320000] | Zp[NWG*32] | Sp[NWG*12800]
    const size_t nfl = ws_size / 4;
    long avail = (long)nfl - (long)(SOUT + RN * CN) - 64;
    int NWG = (int)(avail / (SOUT + 32));
    if (NWG > 512) NWG = 512;
    if (NWG < 1)  NWG = 1;
    const int rpw = (RN + NWG - 1) / NWG;

    float* v  = ws;
    float* b1 = ws + SOUT;
    float* Zp = b1 + (size_t)RN * CN;
    float* Sp = Zp + (size_t)NWG * 32;

    dim3 blk(512), grid(NWG);
    dim3 fblk(256), fgrid((SOUT + 255) / 256);

    // it 0: s0 with uniform c, v0 = squash(s0)
    caps_pass<0><<<grid, blk, 0, stream>>>(x, W, nullptr, nullptr, nullptr, Sp, Zp, rpw);
    caps_finalize<0><<<fgrid, fblk, 0, stream>>>(Sp, Zp, v, NWG);
    // it 1: b1 = mean_b <u_hat,v0>; c1 = softmax(b1); s1; v1
    caps_pass<1><<<grid, blk, 0, stream>>>(x, W, v, nullptr, b1, Sp, Zp, rpw);
    caps_finalize<1><<<fgrid, fblk, 0, stream>>>(Sp, Zp, v, NWG);
    // it 2: b2 = b1 + mean_b <u_hat,v1>; c2 = softmax(b2); s2; v2 -> out
    caps_pass<2><<<grid, blk, 0, stream>>>(x, W, v, b1, nullptr, Sp, Zp, rpw);
    caps_finalize<2><<<fgrid, fblk, 0, stream>>>(Sp, Zp, out, NWG);
}

// Round 2
// 435.351 us; speedup vs baseline: 2.5299x; 2.5299x over previous
//
#include <hip/hip_runtime.h>
#include <cstdint>
#include <cstddef>

// Problem constants
#define RN 12800   // routes
#define CN 25      // caps
#define ON 64      // out channels
#define IN_ 8      // in channels
#define BN 8       // batch
#define SOUT (BN*CN*ON)   // 12800 output elems

#define RPC 64            // routes per chunk
#define NRC (RN / RPC)    // 200 chunks

// Mapping: block = 320 threads = 5 waves. grid = (5, NRC).
// wave w of block (gx, chunk) owns capsule c = gx*5 + w for routes
// [chunk*RPC, (chunk+1)*RPC). lane = o (64 output channels).
//
// MODE 0: iteration 0 (uniform c): acc[b] += u
// MODE 1: b1 = mean_b <u,v0> (store), e = exp(b1), acc[b] += e*u, z += e
// MODE 2: b2 = b1(load) + mean_b <u,v1>, e = exp(b2), acc += e*u, z += e
template<int MODE>
__global__ void __launch_bounds__(320, 6)
caps_pass(const float* __restrict__ x, const float* __restrict__ W,
          const float* __restrict__ vin, const float* __restrict__ bin,
          float* __restrict__ bout, float* __restrict__ Sp, float* __restrict__ Zp)
{
    __shared__ float xs[RPC][BN][IN_];   // 16 KB

    const int chunk = blockIdx.y;
    const int r0 = chunk * RPC;

    // Stage x chunk -> LDS. Global x layout [b][r][i]; LDS [r_local][b][i].
    for (int t = threadIdx.x; t < RPC * BN * 2; t += 320) {
        const int i4 = t & 1;
        const int rl = (t >> 1) & (RPC - 1);
        const int b  = t >> 7;
        const float4 val = *reinterpret_cast<const float4*>(
            x + (((size_t)b * RN + r0 + rl) * IN_) + i4 * 4);
        *reinterpret_cast<float4*>(&xs[rl][b][i4 * 4]) = val;
    }
    __syncthreads();

    const int wave = threadIdx.x >> 6;
    const int lane = threadIdx.x & 63;
    const int c = blockIdx.x * 5 + wave;

    float acc[BN];
    #pragma unroll
    for (int b = 0; b < BN; ++b) acc[b] = 0.f;

    float vreg[BN];
    if (MODE >= 1) {
        #pragma unroll
        for (int b = 0; b < BN; ++b)
            vreg[b] = vin[(b * CN + c) * ON + lane];
    }
    float zacc = 0.f;

    #pragma unroll 2
    for (int rl = 0; rl < RPC; ++rl) {
        const int r = r0 + rl;
        const float4* wp = reinterpret_cast<const float4*>(
            W + ((((size_t)r * CN + c) * ON + lane) * IN_));
        const float4 w0 = wp[0];
        const float4 w1 = wp[1];

        float u[BN];
        #pragma unroll
        for (int b = 0; b < BN; ++b) {
            const float4 xa = *reinterpret_cast<const float4*>(&xs[rl][b][0]);
            const float4 xb = *reinterpret_cast<const float4*>(&xs[rl][b][4]);
            u[b] = w0.x*xa.x + w0.y*xa.y + w0.z*xa.z + w0.w*xa.w
                 + w1.x*xb.x + w1.y*xb.y + w1.z*xb.z + w1.w*xb.w;
        }

        if (MODE == 0) {
            #pragma unroll
            for (int b = 0; b < BN; ++b) acc[b] += u[b];
        } else {
            float p = 0.f;
            #pragma unroll
            for (int b = 0; b < BN; ++b) p += u[b] * vreg[b];
            // sum over the 64 lanes (= sum over o); butterfly, result in all lanes
            #pragma unroll
            for (int off = 32; off > 0; off >>= 1) p += __shfl_xor(p, off, 64);
            float bn = p * (1.0f / BN);
            if (MODE == 2) bn += bin[(size_t)r * CN + c];
            if (MODE == 1 && lane == 0) bout[(size_t)r * CN + c] = bn;
            const float e = __expf(bn);
            zacc += e;
            #pragma unroll
            for (int b = 0; b < BN; ++b) acc[b] += e * u[b];
        }
    }

    // per-(c,chunk) partials
    float* sp = Sp + (size_t)chunk * SOUT;
    #pragma unroll
    for (int b = 0; b < BN; ++b)
        sp[(b * CN + c) * ON + lane] = acc[b];
    if (MODE >= 1 && lane == 0)
        Zp[chunk * 32 + c] = zacc;
}

// PASS 0: z = RN (softmax of zeros over routes); PASS >=1: z from Zp.
template<int PASS>
__global__ void caps_finalize(const float* __restrict__ Sp, const float* __restrict__ Zp,
                              float* __restrict__ vout)
{
    const int idx = blockIdx.x * blockDim.x + threadIdx.x;
    if (idx >= SOUT) return;
    const int c = (idx >> 6) % CN;
    float s = 0.f;
    for (int w = 0; w < NRC; ++w) s += Sp[(size_t)w * SOUT + idx];
    float z;
    if (PASS == 0) {
        z = (float)RN;
    } else {
        z = 0.f;
        for (int w = 0; w < NRC; ++w) z += Zp[w * 32 + c];
    }
    s /= z;
    // squash (elementwise): s*|s|/(1+s^2)
    vout[idx] = s * fabsf(s) / (1.f + s * s);
}

extern "C" void kernel_launch(void* const* d_in, const int* in_sizes, int n_in,
                              void* d_out, int out_size, void* d_ws, size_t ws_size,
                              hipStream_t stream)
{
    const float* x = (const float*)d_in[0];   // [B, R, I]
    const float* W = (const float*)d_in[1];   // [R, C, O, I]
    float* out = (float*)d_out;               // [B, C, O, 1] flat = 12800
    float* ws = (float*)d_ws;

    // Workspace (floats): v[SOUT] | b1[RN*CN] | Zp[NRC*32] | Sp[NRC*SOUT]  (~11.6 MB)
    float* v  = ws;
    float* b1 = ws + SOUT;
    float* Zp = b1 + (size_t)RN * CN;
    float* Sp = Zp + (size_t)NRC * 32;

    dim3 blk(320), grid(5, NRC);
    dim3 fblk(256), fgrid((SOUT + 255) / 256);

    // it 0: s0 with uniform c; v0 = squash(s0)
    caps_pass<0><<<grid, blk, 0, stream>>>(x, W, nullptr, nullptr, nullptr, Sp, Zp);
    caps_finalize<0><<<fgrid, fblk, 0, stream>>>(Sp, Zp, v);
    // it 1: b1 = mean_b <u,v0>; c1 = softmax_r(b1); v1
    caps_pass<1><<<grid, blk, 0, stream>>>(x, W, v, nullptr, b1, Sp, Zp);
    caps_finalize<1><<<fgrid, fblk, 0, stream>>>(Sp, Zp, v);
    // it 2: b2 = b1 + mean_b <u,v1>; c2 = softmax_r(b2); v2 -> out
    caps_pass<2><<<grid, blk, 0, stream>>>(x, W, v, b1, nullptr, Sp, Zp);
    caps_finalize<2><<<fgrid, fblk, 0, stream>>>(Sp, Zp, out);
}

// Round 3
// 384.121 us; speedup vs baseline: 2.8673x; 1.1334x over previous
//
#include <hip/hip_runtime.h>
#include <cstdint>
#include <cstddef>

// Problem constants
#define RN 12800   // routes
#define CN 25      // caps
#define ON 64      // out channels
#define IN_ 8      // in channels
#define BN 8       // batch
#define SOUT (BN*CN*ON)   // 12800 output elems

#define RPC 64            // routes per chunk
#define NRC (RN / RPC)    // 200 chunks

// ---- bf16 helpers (RNE) ----
__device__ __forceinline__ uint32_t pack_bf16(float a, float b) {
    uint32_t ua = __float_as_uint(a);
    uint32_t ub = __float_as_uint(b);
    ua = (ua + 0x7fffu + ((ua >> 16) & 1u)) >> 16;          // bf16(a) in low half
    ub = (ub + 0x7fffu + ((ub >> 16) & 1u)) & 0xffff0000u;  // bf16(b) in high half
    return ua | ub;
}
__device__ __forceinline__ float lo_bf16(uint32_t q) { return __uint_as_float(q << 16); }
__device__ __forceinline__ float hi_bf16(uint32_t q) { return __uint_as_float(q & 0xffff0000u); }

// ============================================================================
// Pass 0: u = W·x per (b,r,c,o); acc S0 (uniform c) AND store u as bf16.
// U layout: [(r*CN+c)*ON + o] * 4 uints  (8 bf16, b-major within the 16B).
// block = 320 thr = 5 waves; wave w owns c = blockIdx.x*5 + w; lane = o.
// ============================================================================
__global__ void __launch_bounds__(320, 6)
caps_pass0(const float* __restrict__ x, const float* __restrict__ W,
           float* __restrict__ Sp, uint32_t* __restrict__ U)
{
    __shared__ float xs[RPC][BN][IN_];   // 16 KB
    const int chunk = blockIdx.y;
    const int r0 = chunk * RPC;

    for (int t = threadIdx.x; t < RPC * BN * 2; t += 320) {
        const int i4 = t & 1;
        const int rl = (t >> 1) & (RPC - 1);
        const int b  = t >> 7;
        const float4 val = *reinterpret_cast<const float4*>(
            x + (((size_t)b * RN + r0 + rl) * IN_) + i4 * 4);
        *reinterpret_cast<float4*>(&xs[rl][b][i4 * 4]) = val;
    }
    __syncthreads();

    const int wave = threadIdx.x >> 6;
    const int lane = threadIdx.x & 63;
    const int c = blockIdx.x * 5 + wave;

    float acc[BN];
    #pragma unroll
    for (int b = 0; b < BN; ++b) acc[b] = 0.f;

    #pragma unroll 2
    for (int rl = 0; rl < RPC; ++rl) {
        const int r = r0 + rl;
        const float4* wp = reinterpret_cast<const float4*>(
            W + ((((size_t)r * CN + c) * ON + lane) * IN_));
        const float4 w0 = wp[0];
        const float4 w1 = wp[1];

        float u[BN];
        #pragma unroll
        for (int b = 0; b < BN; ++b) {
            const float4 xa = *reinterpret_cast<const float4*>(&xs[rl][b][0]);
            const float4 xb = *reinterpret_cast<const float4*>(&xs[rl][b][4]);
            u[b] = w0.x*xa.x + w0.y*xa.y + w0.z*xa.z + w0.w*xa.w
                 + w1.x*xb.x + w1.y*xb.y + w1.z*xb.z + w1.w*xb.w;
            acc[b] += u[b];
        }

        uint4 q;
        q.x = pack_bf16(u[0], u[1]);
        q.y = pack_bf16(u[2], u[3]);
        q.z = pack_bf16(u[4], u[5]);
        q.w = pack_bf16(u[6], u[7]);
        *reinterpret_cast<uint4*>(U + (((size_t)r * CN + c) * ON + lane) * 4) = q;
    }

    float* sp = Sp + (size_t)chunk * SOUT;
    #pragma unroll
    for (int b = 0; b < BN; ++b)
        sp[(b * CN + c) * ON + lane] = acc[b];
}

// ============================================================================
// Pass 1/2 (MODE): read bf16 u_hat only (no W, no x).
// MODE 1: b1 = mean_b <u,v0> (store), e=exp(b1), acc += e*u, z += e
// MODE 2: b2 = b1(load) + mean_b <u,v1>, e=exp(b2), acc += e*u, z += e
// ============================================================================
template<int MODE>
__global__ void __launch_bounds__(320, 6)
caps_passU(const uint32_t* __restrict__ U, const float* __restrict__ vin,
           const float* __restrict__ bin, float* __restrict__ bout,
           float* __restrict__ Sp, float* __restrict__ Zp)
{
    const int chunk = blockIdx.y;
    const int r0 = chunk * RPC;
    const int wave = threadIdx.x >> 6;
    const int lane = threadIdx.x & 63;
    const int c = blockIdx.x * 5 + wave;

    float vreg[BN];
    #pragma unroll
    for (int b = 0; b < BN; ++b)
        vreg[b] = vin[(b * CN + c) * ON + lane];

    float acc[BN];
    #pragma unroll
    for (int b = 0; b < BN; ++b) acc[b] = 0.f;
    float zacc = 0.f;

    #pragma unroll 2
    for (int rl = 0; rl < RPC; ++rl) {
        const int r = r0 + rl;
        const uint4 q = *reinterpret_cast<const uint4*>(
            U + (((size_t)r * CN + c) * ON + lane) * 4);
        float u[BN];
        u[0] = lo_bf16(q.x); u[1] = hi_bf16(q.x);
        u[2] = lo_bf16(q.y); u[3] = hi_bf16(q.y);
        u[4] = lo_bf16(q.z); u[5] = hi_bf16(q.z);
        u[6] = lo_bf16(q.w); u[7] = hi_bf16(q.w);

        float p = 0.f;
        #pragma unroll
        for (int b = 0; b < BN; ++b) p += u[b] * vreg[b];
        // sum over 64 lanes (= sum over o); butterfly, result in all lanes
        #pragma unroll
        for (int off = 32; off > 0; off >>= 1) p += __shfl_xor(p, off, 64);

        float bn = p * (1.0f / BN);
        if (MODE == 2) bn += bin[(size_t)r * CN + c];
        if (MODE == 1 && lane == 0) bout[(size_t)r * CN + c] = bn;
        const float e = __expf(bn);
        zacc += e;
        #pragma unroll
        for (int b = 0; b < BN; ++b) acc[b] += e * u[b];
    }

    float* sp = Sp + (size_t)chunk * SOUT;
    #pragma unroll
    for (int b = 0; b < BN; ++b)
        sp[(b * CN + c) * ON + lane] = acc[b];
    if (lane == 0)
        Zp[chunk * 32 + c] = zacc;
}

// ============================================================================
// Zp pre-reduction: z[c] = sum over 200 chunks. One block of 256 threads.
// ============================================================================
__global__ void caps_zred(const float* __restrict__ Zp, float* __restrict__ z)
{
    __shared__ float l[256];
    const int t = threadIdx.x;
    const int cc = t >> 3;   // 0..31
    const int g  = t & 7;
    float s = 0.f;
    if (cc < CN)
        for (int j = g; j < NRC; j += 8) s += Zp[j * 32 + cc];
    l[t] = s;
    __syncthreads();
    if (g == 0 && cc < CN) {
        float ss = 0.f;
        #pragma unroll
        for (int k = 0; k < 8; ++k) ss += l[cc * 8 + k];
        z[cc] = ss;
    }
}

// ============================================================================
// Finalize: one block per (b,c) pair (200 blocks); 4 waves split the 200
// chunks; LDS reduce; squash; write v (or final out).
// ============================================================================
template<int PASS>
__global__ void __launch_bounds__(256)
caps_fin(const float* __restrict__ Sp, const float* __restrict__ z,
         float* __restrict__ vout)
{
    __shared__ float l[256];
    const int blk = blockIdx.x;          // b*CN + c
    const int t = threadIdx.x;
    const int o = t & 63;
    const int g = t >> 6;                // 0..3
    const int base = blk * 64 + o;
    float s = 0.f;
    for (int w = g * 50; w < g * 50 + 50; ++w)
        s += Sp[(size_t)w * SOUT + base];
    l[t] = s;
    __syncthreads();
    if (g == 0) {
        float ss = l[o] + l[64 + o] + l[128 + o] + l[192 + o];
        const float zz = (PASS == 0) ? (float)RN : z[blk % CN];
        ss /= zz;
        vout[base] = ss * fabsf(ss) / (1.f + ss * ss);
    }
}

extern "C" void kernel_launch(void* const* d_in, const int* in_sizes, int n_in,
                              void* d_out, int out_size, void* d_ws, size_t ws_size,
                              hipStream_t stream)
{
    const float* x = (const float*)d_in[0];   // [B, R, I]
    const float* W = (const float*)d_in[1];   // [R, C, O, I]
    float* out = (float*)d_out;               // [B, C, O, 1] flat = 12800
    float* ws = (float*)d_ws;

    // Workspace (floats unless noted):
    // v[SOUT] | z[32] | b1[RN*CN] | Zp[NRC*32] | Sp[NRC*SOUT] | U (bf16, 4 uints per (r,c,o))
    float* v  = ws;
    float* z  = v + SOUT;
    float* b1 = z + 32;
    float* Zp = b1 + (size_t)RN * CN;
    float* Sp = Zp + (size_t)NRC * 32;
    uint32_t* U = (uint32_t*)(Sp + (size_t)NRC * SOUT);   // RN*CN*ON*4 uints = 327.7 MB

    dim3 blk(320), grid(5, NRC);
    dim3 fblk(256), fgrid(BN * CN);

    // it 0: u = W·x (store bf16), s0 uniform; v0 = squash(s0)
    caps_pass0<<<grid, blk, 0, stream>>>(x, W, Sp, U);
    caps_fin<0><<<fgrid, fblk, 0, stream>>>(Sp, z, v);
    // it 1: b1 = mean_b <u,v0>; c1 = softmax_r(b1); v1
    caps_passU<1><<<grid, blk, 0, stream>>>(U, v, nullptr, b1, Sp, Zp);
    caps_zred<<<1, 256, 0, stream>>>(Zp, z);
    caps_fin<1><<<fgrid, fblk, 0, stream>>>(Sp, z, v);
    // it 2: b2 = b1 + mean_b <u,v1>; c2 = softmax_r(b2); v2 -> out
    caps_passU<2><<<grid, blk, 0, stream>>>(U, v, b1, nullptr, Sp, Zp);
    caps_zred<<<1, 256, 0, stream>>>(Zp, z);
    caps_fin<2><<<fgrid, fblk, 0, stream>>>(Sp, z, out);
}